// Round 1
// baseline (497.076 us; speedup 1.0000x reference)
//
#include <hip/hip_runtime.h>

#define EPSF 1e-5f

__device__ __forceinline__ float clamp01(float x){ return fminf(fmaxf(x, 0.f), 1.f); }

// ---------------- stage 1: conv1(3->32,5x5,pad2) + bn + pool + clamp ----------------
// grid 1024 (1 img/block), block 256 (= 16x16 pooled pixels)
__global__ __launch_bounds__(256) void k_stage1(
    const float* __restrict__ x, const float* __restrict__ w1,
    const float* __restrict__ g, const float* __restrict__ b,
    const float* __restrict__ m, const float* __restrict__ v,
    float* __restrict__ out)
{
  __shared__ float P[3*36*36];          // padded input, 15552 B
  const int img = blockIdx.x;
  const int tid = threadIdx.x;
  const float* xin = x + img*3072;
  for (int i = tid; i < 3*36*36; i += 256) {
    int c = i / 1296, r = i % 1296;
    int y = r / 36, xx = r % 36;
    float val = 0.f;
    if (y >= 2 && y < 34 && xx >= 2 && xx < 34)
      val = xin[c*1024 + (y-2)*32 + (xx-2)];
    P[i] = val;
  }
  __syncthreads();
  const int py = tid >> 4, px = tid & 15;

  // patch sums S[ic][5][5]: each S = sum of input over the 2x2 pool window at that tap
  float S[75];
  #pragma unroll
  for (int ic = 0; ic < 3; ++ic) {
    float p[36];
    const float* Pb = P + ic*1296 + (2*py)*36 + 2*px;
    #pragma unroll
    for (int r = 0; r < 6; ++r) {
      const float2* pr = (const float2*)(Pb + r*36);
      float2 a0 = pr[0], a1 = pr[1], a2 = pr[2];
      p[r*6+0]=a0.x; p[r*6+1]=a0.y; p[r*6+2]=a1.x;
      p[r*6+3]=a1.y; p[r*6+4]=a2.x; p[r*6+5]=a2.y;
    }
    #pragma unroll
    for (int r = 0; r < 5; ++r)
      #pragma unroll
      for (int c = 0; c < 5; ++c)
        S[ic*25 + r*5+c] = (p[r*6+c]+p[r*6+c+1]) + (p[(r+1)*6+c]+p[(r+1)*6+c+1]);
  }

  float* op = out + img*8192 + tid;
  for (int ocb = 0; ocb < 4; ++ocb) {   // runtime uniform loop -> weight addrs stay uniform
    float a[8] = {0,0,0,0,0,0,0,0};
    #pragma unroll
    for (int ic = 0; ic < 3; ++ic)
      #pragma unroll
      for (int j = 0; j < 8; ++j) {
        const float* wj = w1 + ((ocb*8+j)*3 + ic)*25;   // wave-uniform -> s_load
        #pragma unroll
        for (int k = 0; k < 25; ++k)
          a[j] = fmaf(wj[k], S[ic*25+k], a[j]);
      }
    #pragma unroll
    for (int j = 0; j < 8; ++j) {
      int oc = ocb*8 + j;
      float inv = g[oc] / sqrtf(v[oc] + EPSF);
      float beta = b[oc] - m[oc]*inv;
      op[oc*256] = clamp01(fmaf(a[j]*0.25f, inv, beta));
    }
  }
}

// ---------------- stage 2: conv2(32->32,5x5,pad2) + bn + pool + clamp ----------------
// grid 1024 (1 img/block), block 256: lane = pooled pixel (8x8), wave = 8 output chans
__global__ __launch_bounds__(256) void k_stage2(
    const float* __restrict__ xin, const float* __restrict__ w2,
    const float* __restrict__ g, const float* __restrict__ b,
    const float* __restrict__ m, const float* __restrict__ v,
    float* __restrict__ out)
{
  __shared__ float P[32*400];           // 32 x 20 x 20 padded, 51200 B
  const int img = blockIdx.x;
  const int tid = threadIdx.x;
  const float* src = xin + img*8192;
  for (int i = tid; i < 32*400; i += 256) {
    int ic = i / 400, r = i % 400;
    int y = r / 20, xx = r % 20;
    float val = 0.f;
    if (y >= 2 && y < 18 && xx >= 2 && xx < 18)
      val = src[ic*256 + (y-2)*16 + (xx-2)];
    P[i] = val;
  }
  __syncthreads();
  const int w = __builtin_amdgcn_readfirstlane(tid >> 6);  // wave id 0..3 (SGPR)
  const int lane = tid & 63;
  const int py = lane >> 3, px = lane & 7;

  float acc[8] = {0,0,0,0,0,0,0,0};
  for (int ic = 0; ic < 32; ++ic) {     // runtime uniform
    float p[36];
    const float* Pb = P + ic*400 + (2*py)*20 + 2*px;
    #pragma unroll
    for (int r = 0; r < 6; ++r) {
      const float2* pr = (const float2*)(Pb + r*20);
      float2 a0 = pr[0], a1 = pr[1], a2 = pr[2];
      p[r*6+0]=a0.x; p[r*6+1]=a0.y; p[r*6+2]=a1.x;
      p[r*6+3]=a1.y; p[r*6+4]=a2.x; p[r*6+5]=a2.y;
    }
    float S[25];
    #pragma unroll
    for (int r = 0; r < 5; ++r)
      #pragma unroll
      for (int c = 0; c < 5; ++c)
        S[r*5+c] = (p[r*6+c]+p[r*6+c+1]) + (p[(r+1)*6+c]+p[(r+1)*6+c+1]);
    #pragma unroll
    for (int j = 0; j < 8; ++j) {
      const float* wj = w2 + ((w*8+j)*32 + ic)*25;        // wave-uniform -> s_load
      #pragma unroll
      for (int k = 0; k < 25; ++k)
        acc[j] = fmaf(wj[k], S[k], acc[j]);
    }
  }
  float* op = out + img*2048 + lane;
  #pragma unroll
  for (int j = 0; j < 8; ++j) {
    int oc = w*8 + j;
    float inv = g[oc] / sqrtf(v[oc] + EPSF);
    float beta = b[oc] - m[oc]*inv;
    op[oc*64] = clamp01(fmaf(acc[j]*0.25f, inv, beta));
  }
}

// ---------------- stage 3: conv3(32->64,5x5,pad2) + bn + pool + clamp ----------------
// grid 256 (4 img/block), block 256: lane -> (img 0..3, pooled pixel 0..15); wave = 16 ocs
// input channels staged in two chunks of 16 to keep LDS under 64KB
__global__ __launch_bounds__(256) void k_stage3(
    const float* __restrict__ xin, const float* __restrict__ w3,
    const float* __restrict__ g, const float* __restrict__ b,
    const float* __restrict__ m, const float* __restrict__ v,
    float* __restrict__ out)
{
  __shared__ float P[4*2312];           // 4 img x (16 ic x 12 x 12 + 8 pad), 36992 B
  const int i0 = blockIdx.x * 4;
  const int tid = threadIdx.x;
  const int w = __builtin_amdgcn_readfirstlane(tid >> 6);
  const int lane = tid & 63;
  const int img = lane >> 4;
  const int px4 = lane & 15;
  const int py = px4 >> 2, px = px4 & 3;

  float acc[16];
  #pragma unroll
  for (int o = 0; o < 16; ++o) acc[o] = 0.f;

  for (int chunk = 0; chunk < 2; ++chunk) {
    if (chunk) __syncthreads();
    for (int i = tid; i < 4*16*144; i += 256) {
      int im = i / 2304, r = i % 2304;
      int ic2 = r / 144, r2 = r % 144;
      int y = r2 / 12, xx = r2 % 12;
      float val = 0.f;
      if (y >= 2 && y < 10 && xx >= 2 && xx < 10)
        val = xin[(i0+im)*2048 + (chunk*16+ic2)*64 + (y-2)*8 + (xx-2)];
      P[im*2312 + ic2*144 + y*12 + xx] = val;
    }
    __syncthreads();
    for (int ic2 = 0; ic2 < 16; ++ic2) {    // runtime uniform
      float p[36];
      const float* Pb = P + img*2312 + ic2*144 + (2*py)*12 + 2*px;
      #pragma unroll
      for (int r = 0; r < 6; ++r) {
        const float2* pr = (const float2*)(Pb + r*12);
        float2 a0 = pr[0], a1 = pr[1], a2 = pr[2];
        p[r*6+0]=a0.x; p[r*6+1]=a0.y; p[r*6+2]=a1.x;
        p[r*6+3]=a1.y; p[r*6+4]=a2.x; p[r*6+5]=a2.y;
      }
      float S[25];
      #pragma unroll
      for (int r = 0; r < 5; ++r)
        #pragma unroll
        for (int c = 0; c < 5; ++c)
          S[r*5+c] = (p[r*6+c]+p[r*6+c+1]) + (p[(r+1)*6+c]+p[(r+1)*6+c+1]);
      int ic = chunk*16 + ic2;
      #pragma unroll
      for (int o = 0; o < 16; ++o) {
        const float* wo = w3 + ((w*16+o)*32 + ic)*25;     // wave-uniform -> s_load
        #pragma unroll
        for (int k = 0; k < 25; ++k)
          acc[o] = fmaf(wo[k], S[k], acc[o]);
      }
    }
  }
  float* op = out + (i0+img)*1024 + px4;
  #pragma unroll
  for (int o = 0; o < 16; ++o) {
    int oc = w*16 + o;
    float inv = g[oc] / sqrtf(v[oc] + EPSF);
    float beta = b[oc] - m[oc]*inv;
    op[oc*16] = clamp01(fmaf(acc[o]*0.25f, inv, beta));
  }
}

// ---------------- stage 4: fc (4x4 valid conv, 64->10) + bn1d ----------------
// 10240 threads: one per (oc, img); oc wave-uniform -> weights via s_load
__global__ __launch_bounds__(256) void k_stage4(
    const float* __restrict__ xin, const float* __restrict__ w4,
    const float* __restrict__ g, const float* __restrict__ b,
    const float* __restrict__ m, const float* __restrict__ v,
    float* __restrict__ out)
{
  const int gid = blockIdx.x * 256 + threadIdx.x;          // 0..10239
  const int oc = __builtin_amdgcn_readfirstlane(gid >> 10); // uniform per wave
  const int bimg = gid & 1023;
  const float4* xv = (const float4*)(xin + bimg*1024);
  const float4* wv = (const float4*)(w4 + oc*1024);
  float a0=0.f, a1=0.f, a2=0.f, a3=0.f;
  #pragma unroll 4
  for (int k = 0; k < 256; ++k) {
    float4 xk = xv[k]; float4 wk = wv[k];
    a0 = fmaf(xk.x, wk.x, a0); a1 = fmaf(xk.y, wk.y, a1);
    a2 = fmaf(xk.z, wk.z, a2); a3 = fmaf(xk.w, wk.w, a3);
  }
  float acc = (a0+a1) + (a2+a3);
  float inv = g[oc] / sqrtf(v[oc] + EPSF);
  float beta = b[oc] - m[oc]*inv;
  out[bimg*10 + oc] = fmaf(acc, inv, beta);
}

extern "C" void kernel_launch(void* const* d_in, const int* in_sizes, int n_in,
                              void* d_out, int out_size, void* d_ws, size_t ws_size,
                              hipStream_t stream)
{
  const float* x  = (const float*)d_in[0];
  const float* w1 = (const float*)d_in[1];
  const float* w2 = (const float*)d_in[2];
  const float* w3 = (const float*)d_in[3];
  const float* w4 = (const float*)d_in[4];
  const float *g1=(const float*)d_in[5],  *b1=(const float*)d_in[6],
              *m1=(const float*)d_in[7],  *v1=(const float*)d_in[8];
  const float *g2=(const float*)d_in[9],  *b2=(const float*)d_in[10],
              *m2=(const float*)d_in[11], *v2=(const float*)d_in[12];
  const float *g3=(const float*)d_in[13], *b3=(const float*)d_in[14],
              *m3=(const float*)d_in[15], *v3=(const float*)d_in[16];
  const float *g4=(const float*)d_in[17], *b4=(const float*)d_in[18],
              *m4=(const float*)d_in[19], *v4=(const float*)d_in[20];
  float* out = (float*)d_out;

  // workspace layout (floats): s1 [0, 8388608), s2 [8388608, 10485760),
  // s3 overlays s1 (s1 dead once stage2 is done). Total ws need = 42 MB.
  float* s1 = (float*)d_ws;
  float* s2 = s1 + 8388608;
  float* s3 = s1;

  k_stage1<<<dim3(1024), dim3(256), 0, stream>>>(x,  w1, g1, b1, m1, v1, s1);
  k_stage2<<<dim3(1024), dim3(256), 0, stream>>>(s1, w2, g2, b2, m2, v2, s2);
  k_stage3<<<dim3(256),  dim3(256), 0, stream>>>(s2, w3, g3, b3, m3, v3, s3);
  k_stage4<<<dim3(40),   dim3(256), 0, stream>>>(s3, w4, g4, b4, m4, v4, out);
}

// Round 2
// 335.051 us; speedup vs baseline: 1.4836x; 1.4836x over previous
//
#include <hip/hip_runtime.h>

#define EPSF 1e-5f

__device__ __forceinline__ float clamp01(float x){ return fminf(fmaxf(x, 0.f), 1.f); }

// ---------------- stage 1: conv1(3->32,5x5,pad2) + bn + pool + clamp ----------------
// grid 1024 (1 img/block), block 256 (= 16x16 pooled pixels), acc[32] = all ocs
__global__ __launch_bounds__(256) void k_stage1(
    const float* __restrict__ x, const float* __restrict__ w1,
    const float* __restrict__ g, const float* __restrict__ b,
    const float* __restrict__ m, const float* __restrict__ v,
    float* __restrict__ out)
{
  __shared__ __align__(16) float P[3*1296];   // 3 x 36 x 36 padded, 15552 B
  const int img = blockIdx.x;
  const int tid = threadIdx.x;
  const float* xin = x + img*3072;

  // zero (pads), vectorized
  for (int i = tid; i < 972; i += 256) ((float4*)P)[i] = make_float4(0.f,0.f,0.f,0.f);
  __syncthreads();
  // interior fill: 3 ic x 32 rows x 16 float2
  for (int a = tid; a < 1536; a += 256) {
    int ic = a >> 9, r = a & 511;
    int y = r >> 4, q = r & 15;
    float2 val = *(const float2*)(xin + ic*1024 + y*32 + 2*q);
    *(float2*)(P + ic*1296 + (y+2)*36 + 2 + 2*q) = val;
  }
  __syncthreads();

  const int py = tid >> 4, px = tid & 15;
  float acc[32];
  #pragma unroll
  for (int j = 0; j < 32; ++j) acc[j] = 0.f;

  for (int ic = 0; ic < 3; ++ic) {            // runtime uniform
    float p[36];
    const float* Pb = P + ic*1296 + (2*py)*36 + 2*px;
    #pragma unroll
    for (int r = 0; r < 6; ++r) {
      const float2* pr = (const float2*)(Pb + r*36);
      float2 a0 = pr[0], a1 = pr[1], a2 = pr[2];
      p[r*6+0]=a0.x; p[r*6+1]=a0.y; p[r*6+2]=a1.x;
      p[r*6+3]=a1.y; p[r*6+4]=a2.x; p[r*6+5]=a2.y;
    }
    float vt[30];
    #pragma unroll
    for (int r = 0; r < 5; ++r)
      #pragma unroll
      for (int c = 0; c < 6; ++c)
        vt[r*6+c] = p[r*6+c] + p[(r+1)*6+c];
    float S[25];
    #pragma unroll
    for (int r = 0; r < 5; ++r)
      #pragma unroll
      for (int c = 0; c < 5; ++c)
        S[r*5+c] = vt[r*6+c] + vt[r*6+c+1];
    #pragma unroll
    for (int j = 0; j < 32; ++j) {
      const float* wj = w1 + (j*3 + ic)*25;   // wave-uniform -> s_load
      #pragma unroll
      for (int k = 0; k < 25; ++k)
        acc[j] = fmaf(wj[k], S[k], acc[j]);
    }
  }
  float* op = out + img*8192 + tid;
  #pragma unroll
  for (int j = 0; j < 32; ++j) {
    float inv = g[j] / sqrtf(v[j] + EPSF);
    float beta = b[j] - m[j]*inv;
    op[j*256] = clamp01(fmaf(acc[j]*0.25f, inv, beta));
  }
}

// ---------------- stage 2: conv2(32->32,5x5,pad2) + bn + pool + clamp ----------------
// grid 1024 (1 img/block), block 256: lane = pooled pixel (8x8), wave = 8 ocs
// input staged in 2 chunks of 16 ic -> LDS 25.6KB -> 4 blocks/CU resident
__global__ __launch_bounds__(256) void k_stage2(
    const float* __restrict__ xin, const float* __restrict__ w2,
    const float* __restrict__ g, const float* __restrict__ b,
    const float* __restrict__ m, const float* __restrict__ v,
    float* __restrict__ out)
{
  __shared__ __align__(16) float P[16*400];   // 16 x 20 x 20 padded, 25600 B
  const int img = blockIdx.x;
  const int tid = threadIdx.x;
  const float* src = xin + img*8192;

  for (int i = tid; i < 1600; i += 256) ((float4*)P)[i] = make_float4(0.f,0.f,0.f,0.f);

  const int w = __builtin_amdgcn_readfirstlane(tid >> 6);
  const int lane = tid & 63;
  const int py = lane >> 3, px = lane & 7;

  float acc[8] = {0,0,0,0,0,0,0,0};
  for (int chunk = 0; chunk < 2; ++chunk) {
    __syncthreads();                          // zero done / previous compute done
    // interior fill: 16 ic x 16 rows x 8 float2
    for (int a = tid; a < 2048; a += 256) {
      int ic2 = a >> 7, r = a & 127;
      int y = r >> 3, q = r & 7;
      float2 val = *(const float2*)(src + (chunk*16+ic2)*256 + y*16 + 2*q);
      *(float2*)(P + ic2*400 + (y+2)*20 + 2 + 2*q) = val;
    }
    __syncthreads();
    for (int ic2 = 0; ic2 < 16; ++ic2) {      // runtime uniform
      float p[36];
      const float* Pb = P + ic2*400 + (2*py)*20 + 2*px;
      #pragma unroll
      for (int r = 0; r < 6; ++r) {
        const float2* pr = (const float2*)(Pb + r*20);
        float2 a0 = pr[0], a1 = pr[1], a2 = pr[2];
        p[r*6+0]=a0.x; p[r*6+1]=a0.y; p[r*6+2]=a1.x;
        p[r*6+3]=a1.y; p[r*6+4]=a2.x; p[r*6+5]=a2.y;
      }
      float vt[30];
      #pragma unroll
      for (int r = 0; r < 5; ++r)
        #pragma unroll
        for (int c = 0; c < 6; ++c)
          vt[r*6+c] = p[r*6+c] + p[(r+1)*6+c];
      float S[25];
      #pragma unroll
      for (int r = 0; r < 5; ++r)
        #pragma unroll
        for (int c = 0; c < 5; ++c)
          S[r*5+c] = vt[r*6+c] + vt[r*6+c+1];
      #pragma unroll
      for (int j = 0; j < 8; ++j) {
        const float* wj = w2 + ((w*8+j)*32 + chunk*16 + ic2)*25;  // s_load
        #pragma unroll
        for (int k = 0; k < 25; ++k)
          acc[j] = fmaf(wj[k], S[k], acc[j]);
      }
    }
  }
  float* op = out + img*2048 + lane;
  #pragma unroll
  for (int j = 0; j < 8; ++j) {
    int oc = w*8 + j;
    float inv = g[oc] / sqrtf(v[oc] + EPSF);
    float beta = b[oc] - m[oc]*inv;
    op[oc*64] = clamp01(fmaf(acc[j]*0.25f, inv, beta));
  }
}

// ---------------- stage 3: conv3(32->64,5x5,pad2) + bn + pool + clamp ----------------
// grid 1024: block = 4 img x 16 oc (ocb = bid>>8), wave = 4 ocs, lane = (img, px)
// input staged in 2 chunks of 16 ic -> LDS ~37KB -> 4 blocks/CU resident
__global__ __launch_bounds__(256) void k_stage3(
    const float* __restrict__ xin, const float* __restrict__ w3,
    const float* __restrict__ g, const float* __restrict__ b,
    const float* __restrict__ m, const float* __restrict__ v,
    float* __restrict__ out)
{
  __shared__ __align__(16) float P[4*2312];   // 4 img x (16 ic x 12 x 12 + 8 pad)
  const int i0  = (blockIdx.x & 255) * 4;
  const int ocb = (blockIdx.x >> 8) * 16;
  const int tid = threadIdx.x;
  const int w = __builtin_amdgcn_readfirstlane(tid >> 6);
  const int lane = tid & 63;
  const int img = lane >> 4;
  const int px4 = lane & 15;
  const int py = px4 >> 2, px = px4 & 3;

  for (int i = tid; i < 2312; i += 256) ((float4*)P)[i] = make_float4(0.f,0.f,0.f,0.f);

  float acc[4] = {0,0,0,0};
  for (int chunk = 0; chunk < 2; ++chunk) {
    __syncthreads();
    // interior fill: 4 img x 16 ic x 8 rows x 4 float2
    for (int a = tid; a < 2048; a += 256) {
      int im = a >> 9, r = a & 511;
      int ic2 = r >> 5, r2 = r & 31;
      int y = r2 >> 2, q = r2 & 3;
      float2 val = *(const float2*)(xin + (i0+im)*2048 + (chunk*16+ic2)*64 + y*8 + 2*q);
      *(float2*)(P + im*2312 + ic2*144 + (y+2)*12 + 2 + 2*q) = val;
    }
    __syncthreads();
    for (int ic2 = 0; ic2 < 16; ++ic2) {      // runtime uniform
      float p[36];
      const float* Pb = P + img*2312 + ic2*144 + (2*py)*12 + 2*px;
      #pragma unroll
      for (int r = 0; r < 6; ++r) {
        const float2* pr = (const float2*)(Pb + r*12);
        float2 a0 = pr[0], a1 = pr[1], a2 = pr[2];
        p[r*6+0]=a0.x; p[r*6+1]=a0.y; p[r*6+2]=a1.x;
        p[r*6+3]=a1.y; p[r*6+4]=a2.x; p[r*6+5]=a2.y;
      }
      float vt[30];
      #pragma unroll
      for (int r = 0; r < 5; ++r)
        #pragma unroll
        for (int c = 0; c < 6; ++c)
          vt[r*6+c] = p[r*6+c] + p[(r+1)*6+c];
      float S[25];
      #pragma unroll
      for (int r = 0; r < 5; ++r)
        #pragma unroll
        for (int c = 0; c < 5; ++c)
          S[r*5+c] = vt[r*6+c] + vt[r*6+c+1];
      int ic = chunk*16 + ic2;
      #pragma unroll
      for (int o = 0; o < 4; ++o) {
        const float* wo = w3 + ((ocb + w*4 + o)*32 + ic)*25;   // s_load
        #pragma unroll
        for (int k = 0; k < 25; ++k)
          acc[o] = fmaf(wo[k], S[k], acc[o]);
      }
    }
  }
  float* op = out + (i0+img)*1024 + px4;
  #pragma unroll
  for (int o = 0; o < 4; ++o) {
    int oc = ocb + w*4 + o;
    float inv = g[oc] / sqrtf(v[oc] + EPSF);
    float beta = b[oc] - m[oc]*inv;
    op[oc*16] = clamp01(fmaf(acc[o]*0.25f, inv, beta));
  }
}

// ---------------- stage 4: fc (4x4 valid conv, 64->10) + bn1d ----------------
__global__ __launch_bounds__(256) void k_stage4(
    const float* __restrict__ xin, const float* __restrict__ w4,
    const float* __restrict__ g, const float* __restrict__ b,
    const float* __restrict__ m, const float* __restrict__ v,
    float* __restrict__ out)
{
  const int gid = blockIdx.x * 256 + threadIdx.x;            // 0..10239
  const int oc = __builtin_amdgcn_readfirstlane(gid >> 10);  // uniform per wave
  const int bimg = gid & 1023;
  const float4* xv = (const float4*)(xin + bimg*1024);
  const float4* wv = (const float4*)(w4 + oc*1024);
  float a0=0.f, a1=0.f, a2=0.f, a3=0.f;
  #pragma unroll 4
  for (int k = 0; k < 256; ++k) {
    float4 xk = xv[k]; float4 wk = wv[k];
    a0 = fmaf(xk.x, wk.x, a0); a1 = fmaf(xk.y, wk.y, a1);
    a2 = fmaf(xk.z, wk.z, a2); a3 = fmaf(xk.w, wk.w, a3);
  }
  float acc = (a0+a1) + (a2+a3);
  float inv = g[oc] / sqrtf(v[oc] + EPSF);
  float beta = b[oc] - m[oc]*inv;
  out[bimg*10 + oc] = fmaf(acc, inv, beta);
}

extern "C" void kernel_launch(void* const* d_in, const int* in_sizes, int n_in,
                              void* d_out, int out_size, void* d_ws, size_t ws_size,
                              hipStream_t stream)
{
  const float* x  = (const float*)d_in[0];
  const float* w1 = (const float*)d_in[1];
  const float* w2 = (const float*)d_in[2];
  const float* w3 = (const float*)d_in[3];
  const float* w4 = (const float*)d_in[4];
  const float *g1=(const float*)d_in[5],  *b1=(const float*)d_in[6],
              *m1=(const float*)d_in[7],  *v1=(const float*)d_in[8];
  const float *g2=(const float*)d_in[9],  *b2=(const float*)d_in[10],
              *m2=(const float*)d_in[11], *v2=(const float*)d_in[12];
  const float *g3=(const float*)d_in[13], *b3=(const float*)d_in[14],
              *m3=(const float*)d_in[15], *v3=(const float*)d_in[16];
  const float *g4=(const float*)d_in[17], *b4=(const float*)d_in[18],
              *m4=(const float*)d_in[19], *v4=(const float*)d_in[20];
  float* out = (float*)d_out;

  // workspace layout (floats): s1 [0, 8388608), s2 [8388608, 10485760),
  // s3 overlays s1 (s1 dead once stage2 is done).
  float* s1 = (float*)d_ws;
  float* s2 = s1 + 8388608;
  float* s3 = s1;

  k_stage1<<<dim3(1024), dim3(256), 0, stream>>>(x,  w1, g1, b1, m1, v1, s1);
  k_stage2<<<dim3(1024), dim3(256), 0, stream>>>(s1, w2, g2, b2, m2, v2, s2);
  k_stage3<<<dim3(1024), dim3(256), 0, stream>>>(s2, w3, g3, b3, m3, v3, s3);
  k_stage4<<<dim3(40),   dim3(256), 0, stream>>>(s3, w4, g4, b4, m4, v4, out);
}

// Round 3
// 186.542 us; speedup vs baseline: 2.6647x; 1.7961x over previous
//
#include <hip/hip_runtime.h>

#define EPSF 1e-5f

typedef _Float16 half8 __attribute__((ext_vector_type(8)));
typedef _Float16 half2v __attribute__((ext_vector_type(2)));
typedef float f32x4 __attribute__((ext_vector_type(4)));

__device__ __forceinline__ float clamp01(float x){ return fminf(fmaxf(x, 0.f), 1.f); }

// ---------------- prep: weight transpose->f16 + bn constant folding ----------------
// w2h[tap][oc32][ic32], w3h[tap][oc64][ic32], w4h[oc16][k1024] (k = pos*64+ic)
// bnc floats: [0,32) s1scale(incl 1/4) [32,64) s1shift [64,96) s2scale [96,128) s2shift
//             [128,192) s3scale [192,256) s3shift [256,266) s4scale [266,276) s4shift
__global__ __launch_bounds__(256) void k_prep(
    const float* __restrict__ w2, const float* __restrict__ w3, const float* __restrict__ w4,
    const float* __restrict__ g1, const float* __restrict__ b1, const float* __restrict__ m1, const float* __restrict__ v1,
    const float* __restrict__ g2, const float* __restrict__ b2, const float* __restrict__ m2, const float* __restrict__ v2,
    const float* __restrict__ g3, const float* __restrict__ b3, const float* __restrict__ m3, const float* __restrict__ v3,
    const float* __restrict__ g4, const float* __restrict__ b4, const float* __restrict__ m4, const float* __restrict__ v4,
    _Float16* __restrict__ w2h, _Float16* __restrict__ w3h, _Float16* __restrict__ w4h,
    float* __restrict__ bnc)
{
  const int t = blockIdx.x*256 + threadIdx.x;   // grid 128 -> 32768 threads
  for (int i = t; i < 25600; i += 32768) {
    int tap = i >> 10, r = i & 1023, oc = r >> 5, ic = r & 31;
    w2h[i] = (_Float16)w2[(oc*32+ic)*25 + tap];
  }
  for (int i = t; i < 51200; i += 32768) {
    int tap = i >> 11, r = i & 2047, oc = r >> 5, ic = r & 31;
    w3h[i] = (_Float16)w3[(oc*32+ic)*25 + tap];
  }
  for (int i = t; i < 16384; i += 32768) {
    int oc = i >> 10, k = i & 1023, pos = k >> 6, ic = k & 63;
    float val = (oc < 10) ? w4[(oc*64+ic)*16 + pos] : 0.f;
    w4h[i] = (_Float16)val;
  }
  if (t < 32) {
    float inv = g1[t] / sqrtf(v1[t] + EPSF);
    bnc[t] = 0.25f*inv; bnc[32+t] = b1[t] - m1[t]*inv;
    float i2 = g2[t] / sqrtf(v2[t] + EPSF);
    bnc[64+t] = 0.25f*i2; bnc[96+t] = b2[t] - m2[t]*i2;
  }
  if (t < 64) {
    float i3 = g3[t] / sqrtf(v3[t] + EPSF);
    bnc[128+t] = 0.25f*i3; bnc[192+t] = b3[t] - m3[t]*i3;
  }
  if (t < 10) {
    float i4 = g4[t] / sqrtf(v4[t] + EPSF);
    bnc[256+t] = i4; bnc[266+t] = b4[t] - m4[t]*i4;
  }
}

// ---------------- stage 1: conv1(3->32) + bn + pool + clamp (fp32 VALU path) -------
// out: s1h channel-last f16 [img][16][16][32]
__global__ __launch_bounds__(256) void k_stage1(
    const float* __restrict__ x, const float* __restrict__ w1,
    const float* __restrict__ bnc, _Float16* __restrict__ s1h)
{
  __shared__ __align__(16) float P[3*1296];   // 3 x 36 x 36 padded
  const int img = blockIdx.x;
  const int tid = threadIdx.x;
  const float* xin = x + img*3072;

  for (int i = tid; i < 972; i += 256) ((float4*)P)[i] = make_float4(0.f,0.f,0.f,0.f);
  __syncthreads();
  for (int a = tid; a < 1536; a += 256) {
    int ic = a >> 9, r = a & 511;
    int y = r >> 4, q = r & 15;
    float2 val = *(const float2*)(xin + ic*1024 + y*32 + 2*q);
    *(float2*)(P + ic*1296 + (y+2)*36 + 2 + 2*q) = val;
  }
  __syncthreads();

  const int py = tid >> 4, px = tid & 15;
  float acc[32];
  #pragma unroll
  for (int j = 0; j < 32; ++j) acc[j] = 0.f;

  for (int ic = 0; ic < 3; ++ic) {
    float p[36];
    const float* Pb = P + ic*1296 + (2*py)*36 + 2*px;
    #pragma unroll
    for (int r = 0; r < 6; ++r) {
      const float2* pr = (const float2*)(Pb + r*36);
      float2 a0 = pr[0], a1 = pr[1], a2 = pr[2];
      p[r*6+0]=a0.x; p[r*6+1]=a0.y; p[r*6+2]=a1.x;
      p[r*6+3]=a1.y; p[r*6+4]=a2.x; p[r*6+5]=a2.y;
    }
    float vt[30];
    #pragma unroll
    for (int r = 0; r < 5; ++r)
      #pragma unroll
      for (int c = 0; c < 6; ++c)
        vt[r*6+c] = p[r*6+c] + p[(r+1)*6+c];
    float S[25];
    #pragma unroll
    for (int r = 0; r < 5; ++r)
      #pragma unroll
      for (int c = 0; c < 5; ++c)
        S[r*5+c] = vt[r*6+c] + vt[r*6+c+1];
    #pragma unroll
    for (int j = 0; j < 32; ++j) {
      const float* wj = w1 + (j*3 + ic)*25;   // wave-uniform -> s_load
      #pragma unroll
      for (int k = 0; k < 25; ++k)
        acc[j] = fmaf(wj[k], S[k], acc[j]);
    }
  }
  _Float16* op = s1h + img*8192 + tid*32;
  #pragma unroll
  for (int j = 0; j < 32; j += 2) {
    half2v h;
    h[0] = (_Float16)clamp01(fmaf(acc[j],   bnc[j],   bnc[32+j]));
    h[1] = (_Float16)clamp01(fmaf(acc[j+1], bnc[j+1], bnc[32+j+1]));
    *(half2v*)(op + j) = h;
  }
}

// ---------------- stage 2: conv2(32->32) + bn + pool + clamp (MFMA) ----------------
// 1 img/block, 4 waves = 4 M-tiles (16 pooled pixels each), N = 32 (2 tiles)
__global__ __launch_bounds__(256) void k_stage2(
    const _Float16* __restrict__ s1h, const _Float16* __restrict__ w2h,
    const float* __restrict__ bnc, _Float16* __restrict__ s2h)
{
  __shared__ __align__(16) _Float16 Ip[8192];    // [16][16][32]
  __shared__ __align__(16) _Float16 Bx[14440];   // [19][19][40(pad)]
  const int img = blockIdx.x, tid = threadIdx.x;

  // stage input (16KB, coalesced)
  {
    const float4* src = (const float4*)(s1h + img*8192);
    float4* dst = (float4*)Ip;
    #pragma unroll
    for (int i = 0; i < 4; ++i) dst[tid + 256*i] = src[tid + 256*i];
  }
  __syncthreads();

  // dense 2x2 box filter with zero-pad: Bx[y][x][ic] = sum I[y-2..y-1][x-2..x-1]
  const half8* ip = (const half8*)Ip;
  for (int j = tid; j < 1444; j += 256) {
    int pos = j >> 2, kg = j & 3;
    int y = pos / 19, xx = pos - y*19;
    int u = y - 2, v = xx - 2;
    bool r0 = (u >= 0) & (u < 16), r1 = (u >= -1) & (u < 15);
    bool c0 = (v >= 0) & (v < 16), c1 = (v >= -1) & (v < 15);
    half8 z = (half8)(_Float16)0.f;
    half8 a = z, b = z, c = z, d = z;
    if (r0 & c0) a = ip[(u*16+v)*4 + kg];
    if (r0 & c1) b = ip[(u*16+v+1)*4 + kg];
    if (r1 & c0) c = ip[((u+1)*16+v)*4 + kg];
    if (r1 & c1) d = ip[((u+1)*16+v+1)*4 + kg];
    half8 s = (a + b) + (c + d);
    *(half8*)(Bx + pos*40 + kg*8) = s;
  }
  __syncthreads();

  const int w = __builtin_amdgcn_readfirstlane(tid >> 6);
  const int l = tid & 63;
  const int row = l & 15, kg = l >> 4;
  const int p = w*16 + row, py = p >> 3, px = p & 7;

  const _Float16* BxBase = Bx + ((2*py)*19 + 2*px)*40 + kg*8;
  const _Float16* wbase  = w2h + row*32 + kg*8;

  f32x4 acc0 = {0.f,0.f,0.f,0.f}, acc1 = {0.f,0.f,0.f,0.f};
  #pragma unroll
  for (int dy = 0; dy < 5; ++dy)
    #pragma unroll
    for (int dx = 0; dx < 5; ++dx) {
      const int tap = dy*5 + dx;
      half8 av = *(const half8*)(BxBase + (dy*19 + dx)*40);
      half8 b0 = *(const half8*)(wbase + tap*1024);
      half8 b1 = *(const half8*)(wbase + tap*1024 + 512);
      acc0 = __builtin_amdgcn_mfma_f32_16x16x32_f16(av, b0, acc0, 0, 0, 0);
      acc1 = __builtin_amdgcn_mfma_f32_16x16x32_f16(av, b1, acc1, 0, 0, 0);
    }

  // epilogue: C/D col=l&15, row=(l>>4)*4+r
  const int ocl = l & 15;
  const int pr = w*16 + (l >> 4)*4;
  const float s0 = bnc[64 + ocl],      h0 = bnc[96 + ocl];
  const float s1 = bnc[64 + 16 + ocl], h1 = bnc[96 + 16 + ocl];
  _Float16* op = s2h + img*2048;
  #pragma unroll
  for (int r = 0; r < 4; ++r) {
    int p2 = pr + r;
    op[p2*32 + ocl]      = (_Float16)clamp01(fmaf(acc0[r], s0, h0));
    op[p2*32 + 16 + ocl] = (_Float16)clamp01(fmaf(acc1[r], s1, h1));
  }
}

// ---------------- stage 3: conv3(32->64) + bn + pool + clamp (MFMA) ----------------
// 1 img/block, 4 waves = 4 N-tiles; M = 16 pooled pixels (whole image)
__global__ __launch_bounds__(256) void k_stage3(
    const _Float16* __restrict__ s2h, const _Float16* __restrict__ w3h,
    const float* __restrict__ bnc, _Float16* __restrict__ s3h)
{
  __shared__ __align__(16) _Float16 Ip[2048];    // [8][8][32]
  __shared__ __align__(16) _Float16 Bx[4840];    // [11][11][40(pad)]
  const int img = blockIdx.x, tid = threadIdx.x;

  {
    const float4* src = (const float4*)(s2h + img*2048);
    float4* dst = (float4*)Ip;
    dst[tid] = src[tid];
  }
  __syncthreads();

  const half8* ip = (const half8*)Ip;
  for (int j = tid; j < 484; j += 256) {
    int pos = j >> 2, kg = j & 3;
    int y = pos / 11, xx = pos - y*11;
    int u = y - 2, v = xx - 2;
    bool r0 = (u >= 0) & (u < 8), r1 = (u >= -1) & (u < 7);
    bool c0 = (v >= 0) & (v < 8), c1 = (v >= -1) & (v < 7);
    half8 z = (half8)(_Float16)0.f;
    half8 a = z, b = z, c = z, d = z;
    if (r0 & c0) a = ip[(u*8+v)*4 + kg];
    if (r0 & c1) b = ip[(u*8+v+1)*4 + kg];
    if (r1 & c0) c = ip[((u+1)*8+v)*4 + kg];
    if (r1 & c1) d = ip[((u+1)*8+v+1)*4 + kg];
    half8 s = (a + b) + (c + d);
    *(half8*)(Bx + pos*40 + kg*8) = s;
  }
  __syncthreads();

  const int w = __builtin_amdgcn_readfirstlane(tid >> 6);  // N-tile
  const int l = tid & 63;
  const int row = l & 15, kg = l >> 4;
  const int py = row >> 2, px = row & 3;

  const _Float16* BxBase = Bx + ((2*py)*11 + 2*px)*40 + kg*8;
  const _Float16* wbase  = w3h + (w*16 + row)*32 + kg*8;

  f32x4 acc = {0.f,0.f,0.f,0.f};
  #pragma unroll
  for (int dy = 0; dy < 5; ++dy)
    #pragma unroll
    for (int dx = 0; dx < 5; ++dx) {
      const int tap = dy*5 + dx;
      half8 av = *(const half8*)(BxBase + (dy*11 + dx)*40);
      half8 bv = *(const half8*)(wbase + tap*2048);
      acc = __builtin_amdgcn_mfma_f32_16x16x32_f16(av, bv, acc, 0, 0, 0);
    }

  const int oc = w*16 + (l & 15);
  const int pr = (l >> 4)*4;
  const float s3 = bnc[128 + oc], h3 = bnc[192 + oc];
  _Float16* op = s3h + img*1024;
  #pragma unroll
  for (int r = 0; r < 4; ++r)
    op[(pr + r)*64 + oc] = (_Float16)clamp01(fmaf(acc[r], s3, h3));
}

// ---------------- stage 4: fc GEMM [1024img x 1024k x 16oc] + bn1d (MFMA) ----------
__global__ __launch_bounds__(256) void k_stage4(
    const _Float16* __restrict__ s3h, const _Float16* __restrict__ w4h,
    const float* __restrict__ bnc, float* __restrict__ out)
{
  const int gw = (blockIdx.x*256 + threadIdx.x) >> 6;   // 0..63 (img tile)
  const int l = threadIdx.x & 63;
  const int ib = gw*16;
  const int row = l & 15, kg = l >> 4;
  const _Float16* abase = s3h + (ib + row)*1024 + kg*8;
  const _Float16* bbase = w4h + row*1024 + kg*8;

  f32x4 acc = {0.f,0.f,0.f,0.f};
  #pragma unroll 8
  for (int kb = 0; kb < 32; ++kb) {
    half8 av = *(const half8*)(abase + kb*32);
    half8 bv = *(const half8*)(bbase + kb*32);
    acc = __builtin_amdgcn_mfma_f32_16x16x32_f16(av, bv, acc, 0, 0, 0);
  }
  const int oc = l & 15;
  const int ir = ib + (l >> 4)*4;
  if (oc < 10) {
    const float s = bnc[256 + oc], h = bnc[266 + oc];
    #pragma unroll
    for (int r = 0; r < 4; ++r)
      out[(ir + r)*10 + oc] = fmaf(acc[r], s, h);
  }
}

extern "C" void kernel_launch(void* const* d_in, const int* in_sizes, int n_in,
                              void* d_out, int out_size, void* d_ws, size_t ws_size,
                              hipStream_t stream)
{
  const float* x  = (const float*)d_in[0];
  const float* w1 = (const float*)d_in[1];
  const float* w2 = (const float*)d_in[2];
  const float* w3 = (const float*)d_in[3];
  const float* w4 = (const float*)d_in[4];
  const float *g1=(const float*)d_in[5],  *b1=(const float*)d_in[6],
              *m1=(const float*)d_in[7],  *v1=(const float*)d_in[8];
  const float *g2=(const float*)d_in[9],  *b2=(const float*)d_in[10],
              *m2=(const float*)d_in[11], *v2=(const float*)d_in[12];
  const float *g3=(const float*)d_in[13], *b3=(const float*)d_in[14],
              *m3=(const float*)d_in[15], *v3=(const float*)d_in[16];
  const float *g4=(const float*)d_in[17], *b4=(const float*)d_in[18],
              *m4=(const float*)d_in[19], *v4=(const float*)d_in[20];
  float* out = (float*)d_out;

  char* ws = (char*)d_ws;
  _Float16* s1h = (_Float16*)(ws);             // 16,777,216 B
  _Float16* s2h = (_Float16*)(ws + 16777216);  //  4,194,304 B
  _Float16* s3h = (_Float16*)(ws + 20971520);  //  2,097,152 B
  _Float16* w2h = (_Float16*)(ws + 23068672);  //     51,200 B
  _Float16* w3h = (_Float16*)(ws + 23119872);  //    102,400 B
  _Float16* w4h = (_Float16*)(ws + 23222272);  //     32,768 B
  float*    bnc = (float*)   (ws + 23255040);  //      1,152 B

  k_prep<<<dim3(128), dim3(256), 0, stream>>>(w2, w3, w4,
      g1,b1,m1,v1, g2,b2,m2,v2, g3,b3,m3,v3, g4,b4,m4,v4,
      w2h, w3h, w4h, bnc);
  k_stage1<<<dim3(1024), dim3(256), 0, stream>>>(x,   w1,  bnc, s1h);
  k_stage2<<<dim3(1024), dim3(256), 0, stream>>>(s1h, w2h, bnc, s2h);
  k_stage3<<<dim3(1024), dim3(256), 0, stream>>>(s2h, w3h, bnc, s3h);
  k_stage4<<<dim3(16),   dim3(256), 0, stream>>>(s3h, w4h, bnc, out);
}

// Round 5
// 134.918 us; speedup vs baseline: 3.6843x; 1.3826x over previous
//
#include <hip/hip_runtime.h>

#define EPSF 1e-5f

typedef _Float16 half8 __attribute__((ext_vector_type(8)));
typedef _Float16 half4v __attribute__((ext_vector_type(4)));
typedef float f32x4 __attribute__((ext_vector_type(4)));

__device__ __forceinline__ float clamp01(float x){ return fminf(fmaxf(x, 0.f), 1.f); }

// ---------------- prep: weight repack->f16 + bn constant folding ----------------
// w1h[oc32][k160]  k = dy*32 + dx*4 + ic   (ic<3, dx<5 used; rest zero)
// w2h[tap][oc32][ic32], w3h[tap][oc64][ic32], w4h[oc16][k1024] (k = pos*64+ic)
// bnc: [0,32) s1scale(1/4 folded) [32,64) s1shift [64,96) s2scale [96,128) s2shift
//      [128,192) s3scale [192,256) s3shift [256,266) s4scale [266,276) s4shift
__global__ __launch_bounds__(256) void k_prep(
    const float* __restrict__ w1, const float* __restrict__ w2,
    const float* __restrict__ w3, const float* __restrict__ w4,
    const float* __restrict__ g1, const float* __restrict__ b1, const float* __restrict__ m1, const float* __restrict__ v1,
    const float* __restrict__ g2, const float* __restrict__ b2, const float* __restrict__ m2, const float* __restrict__ v2,
    const float* __restrict__ g3, const float* __restrict__ b3, const float* __restrict__ m3, const float* __restrict__ v3,
    const float* __restrict__ g4, const float* __restrict__ b4, const float* __restrict__ m4, const float* __restrict__ v4,
    _Float16* __restrict__ w1h, _Float16* __restrict__ w2h, _Float16* __restrict__ w3h,
    _Float16* __restrict__ w4h, float* __restrict__ bnc)
{
  const int t = blockIdx.x*256 + threadIdx.x;   // grid 128 -> 32768 threads
  if (t < 5120) {                               // w1h: 32 oc x 160 k
    int oc = t / 160, k = t - oc*160;
    int dy = k >> 5, rem = k & 31, dx = rem >> 2, ic = rem & 3;
    float val = (dx < 5 && ic < 3) ? w1[(oc*3+ic)*25 + dy*5 + dx] : 0.f;
    w1h[t] = (_Float16)val;
  }
  for (int i = t; i < 25600; i += 32768) {
    int tap = i >> 10, r = i & 1023, oc = r >> 5, ic = r & 31;
    w2h[i] = (_Float16)w2[(oc*32+ic)*25 + tap];
  }
  for (int i = t; i < 51200; i += 32768) {
    int tap = i >> 11, r = i & 2047, oc = r >> 5, ic = r & 31;
    w3h[i] = (_Float16)w3[(oc*32+ic)*25 + tap];
  }
  for (int i = t; i < 16384; i += 32768) {
    int oc = i >> 10, k = i & 1023, pos = k >> 6, ic = k & 63;
    float val = (oc < 10) ? w4[(oc*64+ic)*16 + pos] : 0.f;
    w4h[i] = (_Float16)val;
  }
  if (t < 32) {
    float inv = g1[t] / sqrtf(v1[t] + EPSF);
    bnc[t] = 0.25f*inv; bnc[32+t] = b1[t] - m1[t]*inv;
    float i2 = g2[t] / sqrtf(v2[t] + EPSF);
    bnc[64+t] = 0.25f*i2; bnc[96+t] = b2[t] - m2[t]*i2;
  }
  if (t < 64) {
    float i3 = g3[t] / sqrtf(v3[t] + EPSF);
    bnc[128+t] = 0.25f*i3; bnc[192+t] = b3[t] - m3[t]*i3;
  }
  if (t < 10) {
    float i4 = g4[t] / sqrtf(v4[t] + EPSF);
    bnc[256+t] = i4; bnc[266+t] = b4[t] - m4[t]*i4;
  }
}

// ---------------- fused: all 4 stages, one image per block ----------------
// LDS arena aliasing (byte offsets):
//   phase1: P f32[36][36][4] @0 (20736)      Bx1 f16[35][144]+pad @20736 (10112)
//           (Bx1 region FULLY zeroed first: stage1 K-pad MFMA reads hit the
//            x=35..36 pad columns and an 8-half overhang; must be 0.0, not
//            garbage -- f16-NaN garbage x 0-weight = NaN poisons the acc)
//   inter : Ip f16[256][32]  @0 (16384)   (over dead P; Bx1 still live)
//   phase2: Bx2 f16[361][40] @16384 (28880)  (over dead Bx1)   -> peak 45264
//   inter : Ip2 f16[64][32]  @0 (4096)
//   phase3: Bx3 f16[121][40] @4096 (9680)    Ip3 f16[16][64] @13776 (2048)
//   phase4: S4P f32[10][16]  @15824 (640)
__global__ __launch_bounds__(256) void k_fused(
    const float* __restrict__ x,
    const _Float16* __restrict__ w1h, const _Float16* __restrict__ w2h,
    const _Float16* __restrict__ w3h, const _Float16* __restrict__ w4h,
    const float* __restrict__ bnc, float* __restrict__ out)
{
  __shared__ __align__(16) char arena[45312];
  float*     P   = (float*)(arena);
  _Float16*  Bx1 = (_Float16*)(arena + 20736);
  _Float16*  Ip  = (_Float16*)(arena);
  _Float16*  Bx2 = (_Float16*)(arena + 16384);
  _Float16*  Ip2 = (_Float16*)(arena);
  _Float16*  Bx3 = (_Float16*)(arena + 4096);
  _Float16*  Ip3 = (_Float16*)(arena + 13776);
  float*     S4P = (float*)(arena + 15824);

  const int img = blockIdx.x;
  const int tid = threadIdx.x;
  const int w   = __builtin_amdgcn_readfirstlane(tid >> 6);
  const int l   = tid & 63;
  const int row = l & 15;          // A-row (pixel) / B-col (oc) / C-col (oc)
  const int kg  = l >> 4;          // k-group

  // ---------- phase 1a: zero P AND entire Bx1 region (contiguous 30848 B) ----------
  for (int i = tid; i < 1928; i += 256)
    ((float4*)arena)[i] = make_float4(0.f,0.f,0.f,0.f);
  __syncthreads();
  {
    const float* xin = x + img*3072;
    #pragma unroll
    for (int rpt = 0; rpt < 3; ++rpt) {
      int i = tid + rpt*256;                  // 768 float4 = [3][32][8]
      int ic = i >> 8, rem = i & 255;
      int y = rem >> 3, xq = rem & 7;
      float4 val = *(const float4*)(xin + ic*1024 + y*32 + xq*4);
      float* dst = P + ((y+2)*36 + xq*4 + 2)*4 + ic;
      dst[0]  = val.x; dst[4]  = val.y; dst[8]  = val.z; dst[12] = val.w;
    }
  }
  __syncthreads();

  // ---------- phase 1b: box filter Bx1[y35][x35*4+ic] (pads stay zero) ----------
  for (int j = tid; j < 1225; j += 256) {
    int y = j / 35, xx = j - y*35;
    const float* p0 = P + (y*36 + xx)*4;
    float4 a = *(const float4*)(p0);
    float4 b = *(const float4*)(p0 + 4);
    float4 c = *(const float4*)(p0 + 144);
    float4 d = *(const float4*)(p0 + 148);
    half4v h;
    h[0] = (_Float16)((a.x + b.x) + (c.x + d.x));
    h[1] = (_Float16)((a.y + b.y) + (c.y + d.y));
    h[2] = (_Float16)((a.z + b.z) + (c.z + d.z));
    h[3] = (_Float16)((a.w + b.w) + (c.w + d.w));
    *(half4v*)(Bx1 + y*144 + xx*4) = h;
  }
  __syncthreads();

  // ---------- phase 1c: s1 MFMA  M=16pix x N=32oc x K=160 (5 chunks) ----------
  {
    half8 B1[5][2];
    #pragma unroll
    for (int dy = 0; dy < 5; ++dy)
      #pragma unroll
      for (int nt = 0; nt < 2; ++nt)
        B1[dy][nt] = *(const half8*)(w1h + (nt*16 + row)*160 + dy*32 + kg*8);

    f32x4 acc[4][2];
    #pragma unroll
    for (int mt = 0; mt < 4; ++mt) { acc[mt][0] = (f32x4){0,0,0,0}; acc[mt][1] = (f32x4){0,0,0,0}; }

    #pragma unroll
    for (int mt = 0; mt < 4; ++mt) {
      const int py = w*4 + mt;
      #pragma unroll
      for (int dy = 0; dy < 5; ++dy) {
        half8 av = *(const half8*)(Bx1 + (2*py + dy)*144 + 8*row + 8*kg);
        acc[mt][0] = __builtin_amdgcn_mfma_f32_16x16x32_f16(av, B1[dy][0], acc[mt][0], 0, 0, 0);
        acc[mt][1] = __builtin_amdgcn_mfma_f32_16x16x32_f16(av, B1[dy][1], acc[mt][1], 0, 0, 0);
      }
    }
    __syncthreads();                      // all Bx1 reads done before Ip overwrites P-region
    const float s0 = bnc[row],      h0 = bnc[32 + row];
    const float s1 = bnc[16 + row], h1 = bnc[48 + row];
    #pragma unroll
    for (int mt = 0; mt < 4; ++mt) {
      #pragma unroll
      for (int r = 0; r < 4; ++r) {
        int pix = (w*4 + mt)*16 + (l>>4)*4 + r;
        Ip[pix*32 + row]      = (_Float16)clamp01(fmaf(acc[mt][0][r], s0, h0));
        Ip[pix*32 + 16 + row] = (_Float16)clamp01(fmaf(acc[mt][1][r], s1, h1));
      }
    }
  }
  __syncthreads();

  // ---------- phase 2a: box filter Bx2[19x19 pos][40] from Ip[16][16][32] ----------
  {
    const half8* ip = (const half8*)Ip;
    for (int j = tid; j < 1444; j += 256) {
      int pos = j >> 2, g = j & 3;
      int y = pos / 19, xx = pos - y*19;
      int u = y - 2, v = xx - 2;
      bool r0 = (u >= 0) & (u < 16), r1 = (u >= -1) & (u < 15);
      bool c0 = (v >= 0) & (v < 16), c1 = (v >= -1) & (v < 15);
      half8 z = (half8)(_Float16)0.f;
      half8 a = z, b = z, c = z, d = z;
      if (r0 & c0) a = ip[(u*16+v)*4 + g];
      if (r0 & c1) b = ip[(u*16+v+1)*4 + g];
      if (r1 & c0) c = ip[((u+1)*16+v)*4 + g];
      if (r1 & c1) d = ip[((u+1)*16+v+1)*4 + g];
      half8 s = (a + b) + (c + d);
      *(half8*)(Bx2 + pos*40 + g*8) = s;
    }
  }
  __syncthreads();

  // ---------- phase 2b: s2 MFMA  25 taps x K=32, N=32 ----------
  {
    const int p = w*16 + row, py = p >> 3, px = p & 7;
    const _Float16* BxBase = Bx2 + ((2*py)*19 + 2*px)*40 + kg*8;
    const _Float16* wbase  = w2h + row*32 + kg*8;
    f32x4 acc0 = {0,0,0,0}, acc1 = {0,0,0,0};
    half8 c0 = *(const half8*)(wbase);
    half8 c1 = *(const half8*)(wbase + 512);
    #pragma unroll
    for (int dy = 0; dy < 5; ++dy)
      #pragma unroll
      for (int dx = 0; dx < 5; ++dx) {
        const int tap = dy*5 + dx;
        const int tn  = (tap < 24) ? tap + 1 : 24;
        half8 n0 = *(const half8*)(wbase + tn*1024);
        half8 n1 = *(const half8*)(wbase + tn*1024 + 512);
        half8 av = *(const half8*)(BxBase + (dy*19 + dx)*40);
        acc0 = __builtin_amdgcn_mfma_f32_16x16x32_f16(av, c0, acc0, 0, 0, 0);
        acc1 = __builtin_amdgcn_mfma_f32_16x16x32_f16(av, c1, acc1, 0, 0, 0);
        c0 = n0; c1 = n1;
      }
    __syncthreads();                      // Bx2 reads done before Ip2 overwrites Ip
    const float s0 = bnc[64 + row],      h0 = bnc[96 + row];
    const float s1 = bnc[64 + 16 + row], h1 = bnc[96 + 16 + row];
    #pragma unroll
    for (int r = 0; r < 4; ++r) {
      int p2 = w*16 + (l >> 4)*4 + r;
      Ip2[p2*32 + row]      = (_Float16)clamp01(fmaf(acc0[r], s0, h0));
      Ip2[p2*32 + 16 + row] = (_Float16)clamp01(fmaf(acc1[r], s1, h1));
    }
  }
  __syncthreads();

  // ---------- phase 3a: box filter Bx3[11x11 pos][40] from Ip2[8][8][32] ----------
  {
    const half8* ip = (const half8*)Ip2;
    for (int j = tid; j < 484; j += 256) {
      int pos = j >> 2, g = j & 3;
      int y = pos / 11, xx = pos - y*11;
      int u = y - 2, v = xx - 2;
      bool r0 = (u >= 0) & (u < 8), r1 = (u >= -1) & (u < 7);
      bool c0 = (v >= 0) & (v < 8), c1 = (v >= -1) & (v < 7);
      half8 z = (half8)(_Float16)0.f;
      half8 a = z, b = z, c = z, d = z;
      if (r0 & c0) a = ip[(u*8+v)*4 + g];
      if (r0 & c1) b = ip[(u*8+v+1)*4 + g];
      if (r1 & c0) c = ip[((u+1)*8+v)*4 + g];
      if (r1 & c1) d = ip[((u+1)*8+v+1)*4 + g];
      half8 s = (a + b) + (c + d);
      *(half8*)(Bx3 + pos*40 + g*8) = s;
    }
  }
  __syncthreads();

  // ---------- phase 3b: s3 MFMA  25 taps x K=32, wave = N-tile (16 of 64 oc) ----------
  {
    const int py = row >> 2, px = row & 3;
    const _Float16* BxBase = Bx3 + ((2*py)*11 + 2*px)*40 + kg*8;
    const _Float16* wbase  = w3h + (w*16 + row)*32 + kg*8;
    f32x4 acc = {0,0,0,0};
    half8 cb = *(const half8*)(wbase);
    #pragma unroll
    for (int dy = 0; dy < 5; ++dy)
      #pragma unroll
      for (int dx = 0; dx < 5; ++dx) {
        const int tap = dy*5 + dx;
        const int tn  = (tap < 24) ? tap + 1 : 24;
        half8 nb = *(const half8*)(wbase + tn*2048);
        half8 av = *(const half8*)(BxBase + (dy*11 + dx)*40);
        acc = __builtin_amdgcn_mfma_f32_16x16x32_f16(av, cb, acc, 0, 0, 0);
        cb = nb;
      }
    const int oc = w*16 + row;
    const float s3 = bnc[128 + oc], h3 = bnc[192 + oc];
    #pragma unroll
    for (int r = 0; r < 4; ++r) {
      int pix = (l >> 4)*4 + r;
      Ip3[pix*64 + oc] = (_Float16)clamp01(fmaf(acc[r], s3, h3));
    }
  }
  __syncthreads();

  // ---------- phase 4: fc 64x4x4 -> 10  + bn1d (VALU, f32 accum) ----------
  if (tid < 160) {
    const int oc = tid >> 4, pix = tid & 15;
    const _Float16* A = Ip3 + pix*64;
    const _Float16* W = w4h + oc*1024 + pix*64;
    float a = 0.f;
    #pragma unroll
    for (int q = 0; q < 8; ++q) {
      half8 xa = *(const half8*)(A + q*8);
      half8 wv = *(const half8*)(W + q*8);
      #pragma unroll
      for (int j = 0; j < 8; ++j)
        a = fmaf((float)xa[j], (float)wv[j], a);
    }
    S4P[tid] = a;
  }
  __syncthreads();
  if (tid < 10) {
    float s = 0.f;
    #pragma unroll
    for (int i = 0; i < 16; ++i) s += S4P[tid*16 + i];
    out[img*10 + tid] = fmaf(s, bnc[256 + tid], bnc[266 + tid]);
  }
}

extern "C" void kernel_launch(void* const* d_in, const int* in_sizes, int n_in,
                              void* d_out, int out_size, void* d_ws, size_t ws_size,
                              hipStream_t stream)
{
  const float* x  = (const float*)d_in[0];
  const float* w1 = (const float*)d_in[1];
  const float* w2 = (const float*)d_in[2];
  const float* w3 = (const float*)d_in[3];
  const float* w4 = (const float*)d_in[4];
  const float *g1=(const float*)d_in[5],  *b1=(const float*)d_in[6],
              *m1=(const float*)d_in[7],  *v1=(const float*)d_in[8];
  const float *g2=(const float*)d_in[9],  *b2=(const float*)d_in[10],
              *m2=(const float*)d_in[11], *v2=(const float*)d_in[12];
  const float *g3=(const float*)d_in[13], *b3=(const float*)d_in[14],
              *m3=(const float*)d_in[15], *v3=(const float*)d_in[16];
  const float *g4=(const float*)d_in[17], *b4=(const float*)d_in[18],
              *m4=(const float*)d_in[19], *v4=(const float*)d_in[20];
  float* out = (float*)d_out;

  char* ws = (char*)d_ws;
  _Float16* w1h = (_Float16*)(ws);             //  10,240 B
  _Float16* w2h = (_Float16*)(ws + 10240);     //  51,200 B
  _Float16* w3h = (_Float16*)(ws + 61440);     // 102,400 B
  _Float16* w4h = (_Float16*)(ws + 163840);    //  32,768 B
  float*    bnc = (float*)   (ws + 196608);    //   1,152 B

  k_prep<<<dim3(128), dim3(256), 0, stream>>>(w1, w2, w3, w4,
      g1,b1,m1,v1, g2,b2,m2,v2, g3,b3,m3,v3, g4,b4,m4,v4,
      w1h, w2h, w3h, w4h, bnc);
  k_fused<<<dim3(1024), dim3(256), 0, stream>>>(x, w1h, w2h, w3h, w4h, bnc, out);
}

// Round 6
// 129.881 us; speedup vs baseline: 3.8272x; 1.0388x over previous
//
#include <hip/hip_runtime.h>

#define EPSF 1e-5f

typedef _Float16 half8 __attribute__((ext_vector_type(8)));
typedef _Float16 half4v __attribute__((ext_vector_type(4)));
typedef float f32x4 __attribute__((ext_vector_type(4)));

__device__ __forceinline__ float clamp01(float x){ return fminf(fmaxf(x, 0.f), 1.f); }

// ---------------- prep: weight repack->f16 + bn constant folding ----------------
// w1h[oc32][k160]  k = dy*32 + dx*4 + ic   (ic<3, dx<5 used; rest zero)
// w2h[tap][oc32][ic32], w3h[tap][oc64][ic32], w4h[oc16][k1024] (k = pos*64+ic)
// bnc: [0,32) s1scale(1/4 folded) [32,64) s1shift [64,96) s2scale [96,128) s2shift
//      [128,192) s3scale [192,256) s3shift [256,266) s4scale [266,276) s4shift
__global__ __launch_bounds__(256) void k_prep(
    const float* __restrict__ w1, const float* __restrict__ w2,
    const float* __restrict__ w3, const float* __restrict__ w4,
    const float* __restrict__ g1, const float* __restrict__ b1, const float* __restrict__ m1, const float* __restrict__ v1,
    const float* __restrict__ g2, const float* __restrict__ b2, const float* __restrict__ m2, const float* __restrict__ v2,
    const float* __restrict__ g3, const float* __restrict__ b3, const float* __restrict__ m3, const float* __restrict__ v3,
    const float* __restrict__ g4, const float* __restrict__ b4, const float* __restrict__ m4, const float* __restrict__ v4,
    _Float16* __restrict__ w1h, _Float16* __restrict__ w2h, _Float16* __restrict__ w3h,
    _Float16* __restrict__ w4h, float* __restrict__ bnc)
{
  const int t = blockIdx.x*256 + threadIdx.x;   // grid 128 -> 32768 threads
  if (t < 5120) {                               // w1h: 32 oc x 160 k
    int oc = t / 160, k = t - oc*160;
    int dy = k >> 5, rem = k & 31, dx = rem >> 2, ic = rem & 3;
    float val = (dx < 5 && ic < 3) ? w1[(oc*3+ic)*25 + dy*5 + dx] : 0.f;
    w1h[t] = (_Float16)val;
  }
  for (int i = t; i < 25600; i += 32768) {
    int tap = i >> 10, r = i & 1023, oc = r >> 5, ic = r & 31;
    w2h[i] = (_Float16)w2[(oc*32+ic)*25 + tap];
  }
  for (int i = t; i < 51200; i += 32768) {
    int tap = i >> 11, r = i & 2047, oc = r >> 5, ic = r & 31;
    w3h[i] = (_Float16)w3[(oc*32+ic)*25 + tap];
  }
  for (int i = t; i < 16384; i += 32768) {
    int oc = i >> 10, k = i & 1023, pos = k >> 6, ic = k & 63;
    float val = (oc < 10) ? w4[(oc*64+ic)*16 + pos] : 0.f;
    w4h[i] = (_Float16)val;
  }
  if (t < 32) {
    float inv = g1[t] / sqrtf(v1[t] + EPSF);
    bnc[t] = 0.25f*inv; bnc[32+t] = b1[t] - m1[t]*inv;
    float i2 = g2[t] / sqrtf(v2[t] + EPSF);
    bnc[64+t] = 0.25f*i2; bnc[96+t] = b2[t] - m2[t]*i2;
  }
  if (t < 64) {
    float i3 = g3[t] / sqrtf(v3[t] + EPSF);
    bnc[128+t] = 0.25f*i3; bnc[192+t] = b3[t] - m3[t]*i3;
  }
  if (t < 10) {
    float i4 = g4[t] / sqrtf(v4[t] + EPSF);
    bnc[256+t] = i4; bnc[266+t] = b4[t] - m4[t]*i4;
  }
}

// ---------------- fused: all 4 stages, one image per block, 7 barriers ----------
// LDS overlays (byte offsets, 32000 B total):
//   ph0-1: Bx1 f16[35][160]          @0     (11200 B)  box-filtered input, from global
//   ph2-3: P2  f16[20][20][40]       @0     (32000 B)  padded s1 output  (over dead Bx1)
//   ph4-5: P3  f16[12][12][40]       @0     (11520 B)  padded s2 output  (over dead P2)
//          Ip3 f16[16][64]           @11520 ( 2048 B)  s3 output
//   ph6:   S4P f32[160]              @13568 (  640 B)
__global__ __launch_bounds__(256, 4) void k_fused(
    const float* __restrict__ x,
    const _Float16* __restrict__ w1h, const _Float16* __restrict__ w2h,
    const _Float16* __restrict__ w3h, const _Float16* __restrict__ w4h,
    const float* __restrict__ bnc, float* __restrict__ out)
{
  __shared__ __align__(16) char arena[32000];
  _Float16* Bx1 = (_Float16*)arena;            // [35][160]
  _Float16* P2  = (_Float16*)arena;            // [20][20][40]
  _Float16* P3  = (_Float16*)arena;            // [12][12][40]
  _Float16* Ip3 = (_Float16*)(arena + 11520);  // [16][64]
  float*    S4P = (float*)(arena + 13568);     // [160]

  const int img = blockIdx.x;
  const int tid = threadIdx.x;
  const int w   = __builtin_amdgcn_readfirstlane(tid >> 6);
  const int l   = tid & 63;
  const int row = l & 15;          // A-row / B-col / C-col lane index
  const int kg  = l >> 4;          // k-group (8 halfs each)

  // ---------- ph0: Bx1[y][x][ic] = 2x2 box of zero-padded input, from global ----------
  // y in 0..34, x in 0..37 (x>=35 are conv-pad taps, computed as zeros arithmetically)
  {
    const float* xin = x + img*3072;
    for (int j = tid; j < 1330; j += 256) {
      int y = j / 38, xx = j - y*38;
      float s0 = 0.f, s1 = 0.f, s2 = 0.f;
      #pragma unroll
      for (int r = 0; r < 2; ++r) {
        int iy = y - 2 + r;
        if ((unsigned)iy < 32u) {
          #pragma unroll
          for (int c = 0; c < 2; ++c) {
            int ix = xx - 2 + c;
            if ((unsigned)ix < 32u) {
              int o = iy*32 + ix;
              s0 += xin[o]; s1 += xin[1024 + o]; s2 += xin[2048 + o];
            }
          }
        }
      }
      half4v h; h[0] = (_Float16)s0; h[1] = (_Float16)s1; h[2] = (_Float16)s2; h[3] = (_Float16)0.f;
      *(half4v*)(Bx1 + y*160 + xx*4) = h;
    }
  }
  __syncthreads();                               // b1: Bx1 ready

  // ---------- ph1: s1 MFMA  M=16 pix-cols x N=32 oc x K=160 (5 dy-chunks) ----------
  f32x4 acc1[4][2];
  {
    half8 B1[5][2];
    #pragma unroll
    for (int dy = 0; dy < 5; ++dy) {
      B1[dy][0] = *(const half8*)(w1h + row*160 + dy*32 + kg*8);
      B1[dy][1] = *(const half8*)(w1h + (16 + row)*160 + dy*32 + kg*8);
    }
    #pragma unroll
    for (int mt = 0; mt < 4; ++mt) { acc1[mt][0] = (f32x4){0,0,0,0}; acc1[mt][1] = (f32x4){0,0,0,0}; }
    const int xoff = 8*(row + kg);               // halfs; 16B aligned
    #pragma unroll
    for (int mt = 0; mt < 4; ++mt) {
      const int py = w*4 + mt;
      #pragma unroll
      for (int dy = 0; dy < 5; ++dy) {
        half8 av = *(const half8*)(Bx1 + (2*py + dy)*160 + xoff);
        acc1[mt][0] = __builtin_amdgcn_mfma_f32_16x16x32_f16(av, B1[dy][0], acc1[mt][0], 0, 0, 0);
        acc1[mt][1] = __builtin_amdgcn_mfma_f32_16x16x32_f16(av, B1[dy][1], acc1[mt][1], 0, 0, 0);
      }
    }
  }
  __syncthreads();                               // b2: all Bx1 reads done

  // ---------- ph2: zero P2 border + write s1 output into P2 interior ----------
  for (int j = tid; j < 1600; j += 256) {        // 400 pos x 4 half8 (ic 0..31)
    int u = j & 3, pos = j >> 2;
    int a = pos/20, c = pos - a*20;
    bool interior = ((unsigned)(a-2) < 16u) & ((unsigned)(c-2) < 16u);
    if (!interior) *(half8*)(P2 + pos*40 + u*8) = (half8)(_Float16)0.f;
  }
  {
    const float s0 = bnc[row],      h0 = bnc[32 + row];
    const float s1 = bnc[16 + row], h1 = bnc[48 + row];
    #pragma unroll
    for (int mt = 0; mt < 4; ++mt) {
      const int py = w*4 + mt;
      #pragma unroll
      for (int r = 0; r < 4; ++r) {
        int pcol = kg*4 + r;
        int idx = ((py+2)*20 + pcol+2)*40;
        P2[idx + row]      = (_Float16)clamp01(fmaf(acc1[mt][0][r], s0, h0));
        P2[idx + 16 + row] = (_Float16)clamp01(fmaf(acc1[mt][1][r], s1, h1));
      }
    }
  }
  __syncthreads();                               // b3: P2 complete

  // ---------- ph3: s2 MFMA, A-frags on the fly (rolling 2-row window) ----------
  f32x4 a2_0 = {0,0,0,0}, a2_1 = {0,0,0,0};
  {
    const int pixel = w*16 + row;
    const int py = pixel >> 3, px = pixel & 7;
    const _Float16* base = P2 + ((2*py)*20 + 2*px)*40 + kg*8;
    half8 RA[6], RB[6];
    #pragma unroll
    for (int c = 0; c < 6; ++c) RA[c] = *(const half8*)(base + c*40);
    #pragma unroll
    for (int c = 0; c < 6; ++c) RB[c] = *(const half8*)(base + 800 + c*40);
    const _Float16* wb = w2h + row*32 + kg*8;
    half8 cw0 = *(const half8*)(wb);
    half8 cw1 = *(const half8*)(wb + 512);
    #pragma unroll
    for (int dy = 0; dy < 5; ++dy) {
      half8 cs[6];
      #pragma unroll
      for (int c = 0; c < 6; ++c) cs[c] = RA[c] + RB[c];
      if (dy < 4) {
        #pragma unroll
        for (int c = 0; c < 6; ++c) {
          half8 nv = *(const half8*)(base + (dy+2)*800 + c*40);
          if ((dy & 1) == 0) RA[c] = nv; else RB[c] = nv;
        }
      }
      #pragma unroll
      for (int dx = 0; dx < 5; ++dx) {
        const int tap = dy*5 + dx;
        const int tn = (tap < 24) ? tap + 1 : 24;
        half8 nw0 = *(const half8*)(wb + tn*1024);
        half8 nw1 = *(const half8*)(wb + tn*1024 + 512);
        half8 av = cs[dx] + cs[dx+1];
        a2_0 = __builtin_amdgcn_mfma_f32_16x16x32_f16(av, cw0, a2_0, 0, 0, 0);
        a2_1 = __builtin_amdgcn_mfma_f32_16x16x32_f16(av, cw1, a2_1, 0, 0, 0);
        cw0 = nw0; cw1 = nw1;
      }
    }
  }
  __syncthreads();                               // b4: all P2 reads done

  // ---------- ph4: zero P3 border + write s2 output into P3 interior ----------
  for (int j = tid; j < 576; j += 256) {         // 144 pos x 4 half8
    int u = j & 3, pos = j >> 2;
    int a = pos/12, c = pos - a*12;
    bool interior = ((unsigned)(a-2) < 8u) & ((unsigned)(c-2) < 8u);
    if (!interior) *(half8*)(P3 + pos*40 + u*8) = (half8)(_Float16)0.f;
  }
  {
    const float s0 = bnc[64 + row], h0 = bnc[96 + row];
    const float s1 = bnc[80 + row], h1 = bnc[112 + row];
    #pragma unroll
    for (int r = 0; r < 4; ++r) {
      int p2 = w*16 + kg*4 + r;
      int py2 = p2 >> 3, px2 = p2 & 7;
      int idx = ((py2+2)*12 + px2+2)*40;
      P3[idx + row]      = (_Float16)clamp01(fmaf(a2_0[r], s0, h0));
      P3[idx + 16 + row] = (_Float16)clamp01(fmaf(a2_1[r], s1, h1));
    }
  }
  __syncthreads();                               // b5: P3 complete

  // ---------- ph5: s3 MFMA on the fly, wave = 16-oc N-tile; epilogue -> Ip3 ----------
  {
    const int py = row >> 2, px = row & 3;
    const _Float16* base = P3 + ((2*py)*12 + 2*px)*40 + kg*8;
    half8 RA[6], RB[6];
    #pragma unroll
    for (int c = 0; c < 6; ++c) RA[c] = *(const half8*)(base + c*40);
    #pragma unroll
    for (int c = 0; c < 6; ++c) RB[c] = *(const half8*)(base + 480 + c*40);
    const _Float16* wb = w3h + (w*16 + row)*32 + kg*8;
    half8 cw = *(const half8*)(wb);
    f32x4 a3 = {0,0,0,0};
    #pragma unroll
    for (int dy = 0; dy < 5; ++dy) {
      half8 cs[6];
      #pragma unroll
      for (int c = 0; c < 6; ++c) cs[c] = RA[c] + RB[c];
      if (dy < 4) {
        #pragma unroll
        for (int c = 0; c < 6; ++c) {
          half8 nv = *(const half8*)(base + (dy+2)*480 + c*40);
          if ((dy & 1) == 0) RA[c] = nv; else RB[c] = nv;
        }
      }
      #pragma unroll
      for (int dx = 0; dx < 5; ++dx) {
        const int tap = dy*5 + dx;
        const int tn = (tap < 24) ? tap + 1 : 24;
        half8 nw = *(const half8*)(wb + tn*2048);
        half8 av = cs[dx] + cs[dx+1];
        a3 = __builtin_amdgcn_mfma_f32_16x16x32_f16(av, cw, a3, 0, 0, 0);
        cw = nw;
      }
    }
    const int oc = w*16 + row;
    const float s3 = bnc[128 + oc], h3 = bnc[192 + oc];
    #pragma unroll
    for (int r = 0; r < 4; ++r)
      Ip3[(kg*4 + r)*64 + oc] = (_Float16)clamp01(fmaf(a3[r], s3, h3));   // disjoint from P3
  }
  __syncthreads();                               // b6: Ip3 complete

  // ---------- ph6: fc 64x4x4 -> 10  + bn1d (VALU, f32 accum) ----------
  if (tid < 160) {
    const int oc = tid >> 4, pix = tid & 15;
    const _Float16* A = Ip3 + pix*64;
    const _Float16* W = w4h + oc*1024 + pix*64;
    float a = 0.f;
    #pragma unroll
    for (int q = 0; q < 8; ++q) {
      half8 xa = *(const half8*)(A + q*8);
      half8 wv = *(const half8*)(W + q*8);
      #pragma unroll
      for (int j = 0; j < 8; ++j)
        a = fmaf((float)xa[j], (float)wv[j], a);
    }
    S4P[tid] = a;
  }
  __syncthreads();                               // b7
  if (tid < 10) {
    float s = 0.f;
    #pragma unroll
    for (int i = 0; i < 16; ++i) s += S4P[tid*16 + i];
    out[img*10 + tid] = fmaf(s, bnc[256 + tid], bnc[266 + tid]);
  }
}

extern "C" void kernel_launch(void* const* d_in, const int* in_sizes, int n_in,
                              void* d_out, int out_size, void* d_ws, size_t ws_size,
                              hipStream_t stream)
{
  const float* x  = (const float*)d_in[0];
  const float* w1 = (const float*)d_in[1];
  const float* w2 = (const float*)d_in[2];
  const float* w3 = (const float*)d_in[3];
  const float* w4 = (const float*)d_in[4];
  const float *g1=(const float*)d_in[5],  *b1=(const float*)d_in[6],
              *m1=(const float*)d_in[7],  *v1=(const float*)d_in[8];
  const float *g2=(const float*)d_in[9],  *b2=(const float*)d_in[10],
              *m2=(const float*)d_in[11], *v2=(const float*)d_in[12];
  const float *g3=(const float*)d_in[13], *b3=(const float*)d_in[14],
              *m3=(const float*)d_in[15], *v3=(const float*)d_in[16];
  const float *g4=(const float*)d_in[17], *b4=(const float*)d_in[18],
              *m4=(const float*)d_in[19], *v4=(const float*)d_in[20];
  float* out = (float*)d_out;

  char* ws = (char*)d_ws;
  _Float16* w1h = (_Float16*)(ws);             //  10,240 B
  _Float16* w2h = (_Float16*)(ws + 10240);     //  51,200 B
  _Float16* w3h = (_Float16*)(ws + 61440);     // 102,400 B
  _Float16* w4h = (_Float16*)(ws + 163840);    //  32,768 B
  float*    bnc = (float*)   (ws + 196608);    //   1,152 B

  k_prep<<<dim3(128), dim3(256), 0, stream>>>(w1, w2, w3, w4,
      g1,b1,m1,v1, g2,b2,m2,v2, g3,b3,m3,v3, g4,b4,m4,v4,
      w1h, w2h, w3h, w4h, bnc);
  k_fused<<<dim3(1024), dim3(256), 0, stream>>>(x, w1h, w2h, w3h, w4h, bnc, out);
}

// Round 7
// 126.882 us; speedup vs baseline: 3.9176x; 1.0236x over previous
//
#include <hip/hip_runtime.h>

#define EPSF 1e-5f

typedef _Float16 half8 __attribute__((ext_vector_type(8)));
typedef _Float16 half4v __attribute__((ext_vector_type(4)));
typedef _Float16 half2v __attribute__((ext_vector_type(2)));
typedef float f32x4 __attribute__((ext_vector_type(4)));

__device__ __forceinline__ float clamp01(float x){ return fminf(fmaxf(x, 0.f), 1.f); }

// ---------------- prep: weight repack->f16 + bn constant folding ----------------
// Column pairing: B-tile0 col n holds oc=2n, tile1 col n holds oc=2n+1, so each
// lane's two outputs are ADJACENT channels -> half2 epilogue stores.
// w1h[col32][k160]  k = dy*32 + dx*4 + ic (ic<3, dx<5 used; rest zero)
// w2h[tap][col32][ic32], w3h[tap][oc64][ic32] (natural), w4h[oc16][k1024]
// bnc: [0,32) s1scale(1/4 folded) [32,64) s1shift [64,96) s2scale [96,128) s2shift
//      [128,192) s3scale [192,256) s3shift [256,266) s4scale [266,276) s4shift
__global__ __launch_bounds__(256) void k_prep(
    const float* __restrict__ w1, const float* __restrict__ w2,
    const float* __restrict__ w3, const float* __restrict__ w4,
    const float* __restrict__ g1, const float* __restrict__ b1, const float* __restrict__ m1, const float* __restrict__ v1,
    const float* __restrict__ g2, const float* __restrict__ b2, const float* __restrict__ m2, const float* __restrict__ v2,
    const float* __restrict__ g3, const float* __restrict__ b3, const float* __restrict__ m3, const float* __restrict__ v3,
    const float* __restrict__ g4, const float* __restrict__ b4, const float* __restrict__ m4, const float* __restrict__ v4,
    _Float16* __restrict__ w1h, _Float16* __restrict__ w2h, _Float16* __restrict__ w3h,
    _Float16* __restrict__ w4h, float* __restrict__ bnc)
{
  const int t = blockIdx.x*256 + threadIdx.x;   // grid 128 -> 32768 threads
  if (t < 5120) {                               // w1h: 32 cols x 160 k
    int c = t / 160, k = t - c*160;
    int oc = (c < 16) ? 2*c : 2*(c-16)+1;
    int dy = k >> 5, rem = k & 31, dx = rem >> 2, ic = rem & 3;
    float val = (dx < 5 && ic < 3) ? w1[(oc*3+ic)*25 + dy*5 + dx] : 0.f;
    w1h[t] = (_Float16)val;
  }
  for (int i = t; i < 25600; i += 32768) {
    int tap = i >> 10, r = i & 1023, c = r >> 5, ic = r & 31;
    int oc = (c < 16) ? 2*c : 2*(c-16)+1;
    w2h[i] = (_Float16)w2[(oc*32+ic)*25 + tap];
  }
  for (int i = t; i < 51200; i += 32768) {
    int tap = i >> 11, r = i & 2047, oc = r >> 5, ic = r & 31;
    w3h[i] = (_Float16)w3[(oc*32+ic)*25 + tap];
  }
  for (int i = t; i < 16384; i += 32768) {
    int oc = i >> 10, k = i & 1023, pos = k >> 6, ic = k & 63;
    float val = (oc < 10) ? w4[(oc*64+ic)*16 + pos] : 0.f;
    w4h[i] = (_Float16)val;
  }
  if (t < 32) {
    float inv = g1[t] / sqrtf(v1[t] + EPSF);
    bnc[t] = 0.25f*inv; bnc[32+t] = b1[t] - m1[t]*inv;
    float i2 = g2[t] / sqrtf(v2[t] + EPSF);
    bnc[64+t] = 0.25f*i2; bnc[96+t] = b2[t] - m2[t]*i2;
  }
  if (t < 64) {
    float i3 = g3[t] / sqrtf(v3[t] + EPSF);
    bnc[128+t] = 0.25f*i3; bnc[192+t] = b3[t] - m3[t]*i3;
  }
  if (t < 10) {
    float i4 = g4[t] / sqrtf(v4[t] + EPSF);
    bnc[256+t] = i4; bnc[266+t] = b4[t] - m4[t]*i4;
  }
}

// ---------------- fused: all 4 stages, one image per block, 8 barriers ----------
// LDS overlays (byte offsets, 32000 B total):
//   ph0:   Bx1 f16[35][160] @0 (11200)   Img f32[3][32][32] @11264 (12288)
//   ph2-3: P2  f16[20][20][40] @0 (32000)  padded s1 output (over dead Bx1+Img)
//   ph4-5: P3  f16[12][12][40] @0 (11520)  padded s2 output (over dead P2)
//          Ip3 f16[16][64] @11520 (2048)
//   ph6:   S4P f32[160] @13568 (640)
__global__ __launch_bounds__(256, 4) void k_fused(
    const float* __restrict__ x,
    const _Float16* __restrict__ w1h, const _Float16* __restrict__ w2h,
    const _Float16* __restrict__ w3h, const _Float16* __restrict__ w4h,
    const float* __restrict__ bnc, float* __restrict__ out)
{
  __shared__ __align__(16) char arena[32000];
  _Float16* Bx1 = (_Float16*)arena;            // [35][160]
  float*    Img = (float*)(arena + 11264);     // [3][32][32] f32
  _Float16* P2  = (_Float16*)arena;            // [20][20][40]
  _Float16* P3  = (_Float16*)arena;            // [12][12][40]
  _Float16* Ip3 = (_Float16*)(arena + 11520);  // [16][64]
  float*    S4P = (float*)(arena + 13568);     // [160]

  const int img = blockIdx.x;
  const int tid = threadIdx.x;
  const int w   = __builtin_amdgcn_readfirstlane(tid >> 6);
  const int l   = tid & 63;
  const int row = l & 15;          // A-row / B-col / C-col lane index
  const int kg  = l >> 4;          // k-group (8 halfs each)

  // ---------- ph0a: coalesced image stage (fp32, 12KB) ----------
  {
    const float4* src = (const float4*)(x + img*3072);
    float4* dst = (float4*)Img;
    dst[tid] = src[tid]; dst[tid+256] = src[tid+256]; dst[tid+512] = src[tid+512];
  }
  __syncthreads();                               // b0: Img ready

  // ---------- ph0b: Bx1[y][x][ic] = 2x2 box of zero-padded input (from LDS) ----------
  for (int j = tid; j < 1400; j += 256) {        // y<35, x<40 (x>=34 all-zero taps)
    int y = j / 40, xx = j - y*40;
    float s0 = 0.f, s1 = 0.f, s2 = 0.f;
    #pragma unroll
    for (int r = 0; r < 2; ++r) {
      int iy = y - 2 + r;
      if ((unsigned)iy < 32u) {
        #pragma unroll
        for (int cc = 0; cc < 2; ++cc) {
          int ix = xx - 2 + cc;
          if ((unsigned)ix < 32u) {
            const float* ip = Img + iy*32 + ix;
            s0 += ip[0]; s1 += ip[1024]; s2 += ip[2048];
          }
        }
      }
    }
    half4v h; h[0] = (_Float16)s0; h[1] = (_Float16)s1; h[2] = (_Float16)s2; h[3] = (_Float16)0.f;
    *(half4v*)(Bx1 + y*160 + xx*4) = h;
  }
  __syncthreads();                               // b1: Bx1 ready

  // ---------- ph1: s1 MFMA  M=16 pix-cols x N=32 oc x K=160 (5 dy-chunks) ----------
  f32x4 acc1[4][2];
  {
    half8 B1[5][2];
    #pragma unroll
    for (int dy = 0; dy < 5; ++dy) {
      B1[dy][0] = *(const half8*)(w1h + row*160 + dy*32 + kg*8);
      B1[dy][1] = *(const half8*)(w1h + (16 + row)*160 + dy*32 + kg*8);
    }
    #pragma unroll
    for (int mt = 0; mt < 4; ++mt) { acc1[mt][0] = (f32x4){0,0,0,0}; acc1[mt][1] = (f32x4){0,0,0,0}; }
    const int xoff = 8*(row + kg);               // halfs; 16B aligned
    #pragma unroll
    for (int mt = 0; mt < 4; ++mt) {
      const int py = w*4 + mt;
      #pragma unroll
      for (int dy = 0; dy < 5; ++dy) {
        half8 av = *(const half8*)(Bx1 + (2*py + dy)*160 + xoff);
        acc1[mt][0] = __builtin_amdgcn_mfma_f32_16x16x32_f16(av, B1[dy][0], acc1[mt][0], 0, 0, 0);
        acc1[mt][1] = __builtin_amdgcn_mfma_f32_16x16x32_f16(av, B1[dy][1], acc1[mt][1], 0, 0, 0);
      }
    }
  }
  __syncthreads();                               // b2: all Bx1 reads done

  // ---------- ph2: zero P2 border + write s1 output (half2 pairs, oc=2n/2n+1) ----------
  for (int j = tid; j < 1600; j += 256) {        // 400 pos x 4 half8 (ic 0..31)
    int u = j & 3, pos = j >> 2;
    int a = pos/20, c = pos - a*20;
    bool interior = ((unsigned)(a-2) < 16u) & ((unsigned)(c-2) < 16u);
    if (!interior) *(half8*)(P2 + pos*40 + u*8) = (half8)(_Float16)0.f;
  }
  {
    const int oce = 2*row;
    const float sA = bnc[oce],   hA = bnc[32 + oce];
    const float sB = bnc[oce+1], hB = bnc[32 + oce + 1];
    #pragma unroll
    for (int mt = 0; mt < 4; ++mt) {
      const int py = w*4 + mt;
      #pragma unroll
      for (int r = 0; r < 4; ++r) {
        int pcol = kg*4 + r;
        int idx = ((py+2)*20 + pcol+2)*40;
        half2v h;
        h[0] = (_Float16)clamp01(fmaf(acc1[mt][0][r], sA, hA));
        h[1] = (_Float16)clamp01(fmaf(acc1[mt][1][r], sB, hB));
        *(half2v*)(P2 + idx + oce) = h;
      }
    }
  }
  __syncthreads();                               // b3: P2 complete

  // ---------- ph3: s2 MFMA, A-frags on the fly (rolling 2-row window) ----------
  f32x4 a2_0 = {0,0,0,0}, a2_1 = {0,0,0,0};
  {
    const int pixel = w*16 + row;
    const int py = pixel >> 3, px = pixel & 7;
    const _Float16* base = P2 + ((2*py)*20 + 2*px)*40 + kg*8;
    half8 RA[6], RB[6];
    #pragma unroll
    for (int c = 0; c < 6; ++c) RA[c] = *(const half8*)(base + c*40);
    #pragma unroll
    for (int c = 0; c < 6; ++c) RB[c] = *(const half8*)(base + 800 + c*40);
    const _Float16* wb = w2h + row*32 + kg*8;
    half8 cw0 = *(const half8*)(wb);
    half8 cw1 = *(const half8*)(wb + 512);
    #pragma unroll
    for (int dy = 0; dy < 5; ++dy) {
      half8 cs[6];
      #pragma unroll
      for (int c = 0; c < 6; ++c) cs[c] = RA[c] + RB[c];
      if (dy < 4) {
        #pragma unroll
        for (int c = 0; c < 6; ++c) {
          half8 nv = *(const half8*)(base + (dy+2)*800 + c*40);
          if ((dy & 1) == 0) RA[c] = nv; else RB[c] = nv;
        }
      }
      #pragma unroll
      for (int dx = 0; dx < 5; ++dx) {
        const int tap = dy*5 + dx;
        const int tn = (tap < 24) ? tap + 1 : 24;
        half8 nw0 = *(const half8*)(wb + tn*1024);
        half8 nw1 = *(const half8*)(wb + tn*1024 + 512);
        half8 av = cs[dx] + cs[dx+1];
        a2_0 = __builtin_amdgcn_mfma_f32_16x16x32_f16(av, cw0, a2_0, 0, 0, 0);
        a2_1 = __builtin_amdgcn_mfma_f32_16x16x32_f16(av, cw1, a2_1, 0, 0, 0);
        cw0 = nw0; cw1 = nw1;
      }
    }
  }
  __syncthreads();                               // b4: all P2 reads done

  // ---------- ph4: zero P3 border + write s2 output (half2 pairs) ----------
  for (int j = tid; j < 576; j += 256) {         // 144 pos x 4 half8
    int u = j & 3, pos = j >> 2;
    int a = pos/12, c = pos - a*12;
    bool interior = ((unsigned)(a-2) < 8u) & ((unsigned)(c-2) < 8u);
    if (!interior) *(half8*)(P3 + pos*40 + u*8) = (half8)(_Float16)0.f;
  }
  {
    const int oce = 2*row;
    const float sA = bnc[64 + oce],   hA = bnc[96 + oce];
    const float sB = bnc[64 + oce+1], hB = bnc[96 + oce + 1];
    #pragma unroll
    for (int r = 0; r < 4; ++r) {
      int p2 = w*16 + kg*4 + r;
      int py2 = p2 >> 3, px2 = p2 & 7;
      int idx = ((py2+2)*12 + px2+2)*40;
      half2v h;
      h[0] = (_Float16)clamp01(fmaf(a2_0[r], sA, hA));
      h[1] = (_Float16)clamp01(fmaf(a2_1[r], sB, hB));
      *(half2v*)(P3 + idx + oce) = h;
    }
  }
  __syncthreads();                               // b5: P3 complete

  // ---------- ph5: s3 MFMA on the fly, wave = 16-oc N-tile; epilogue -> Ip3 ----------
  {
    const int py = row >> 2, px = row & 3;
    const _Float16* base = P3 + ((2*py)*12 + 2*px)*40 + kg*8;
    half8 RA[6], RB[6];
    #pragma unroll
    for (int c = 0; c < 6; ++c) RA[c] = *(const half8*)(base + c*40);
    #pragma unroll
    for (int c = 0; c < 6; ++c) RB[c] = *(const half8*)(base + 480 + c*40);
    const _Float16* wb = w3h + (w*16 + row)*32 + kg*8;
    half8 cw = *(const half8*)(wb);
    f32x4 a3 = {0,0,0,0};
    #pragma unroll
    for (int dy = 0; dy < 5; ++dy) {
      half8 cs[6];
      #pragma unroll
      for (int c = 0; c < 6; ++c) cs[c] = RA[c] + RB[c];
      if (dy < 4) {
        #pragma unroll
        for (int c = 0; c < 6; ++c) {
          half8 nv = *(const half8*)(base + (dy+2)*480 + c*40);
          if ((dy & 1) == 0) RA[c] = nv; else RB[c] = nv;
        }
      }
      #pragma unroll
      for (int dx = 0; dx < 5; ++dx) {
        const int tap = dy*5 + dx;
        const int tn = (tap < 24) ? tap + 1 : 24;
        half8 nw = *(const half8*)(wb + tn*2048);
        half8 av = cs[dx] + cs[dx+1];
        a3 = __builtin_amdgcn_mfma_f32_16x16x32_f16(av, cw, a3, 0, 0, 0);
        cw = nw;
      }
    }
    const int oc = w*16 + row;
    const float s3 = bnc[128 + oc], h3 = bnc[192 + oc];
    #pragma unroll
    for (int r = 0; r < 4; ++r)
      Ip3[(kg*4 + r)*64 + oc] = (_Float16)clamp01(fmaf(a3[r], s3, h3));
  }
  __syncthreads();                               // b6: Ip3 complete

  // ---------- ph6: fc 64x4x4 -> 10  + bn1d (VALU, f32 accum) ----------
  if (tid < 160) {
    const int oc = tid >> 4, pix = tid & 15;
    const _Float16* A = Ip3 + pix*64;
    const _Float16* W = w4h + oc*1024 + pix*64;
    float a = 0.f;
    #pragma unroll
    for (int q = 0; q < 8; ++q) {
      half8 xa = *(const half8*)(A + q*8);
      half8 wv = *(const half8*)(W + q*8);
      #pragma unroll
      for (int j = 0; j < 8; ++j)
        a = fmaf((float)xa[j], (float)wv[j], a);
    }
    S4P[tid] = a;
  }
  __syncthreads();                               // b7
  if (tid < 10) {
    float s = 0.f;
    #pragma unroll
    for (int i = 0; i < 16; ++i) s += S4P[tid*16 + i];
    out[img*10 + tid] = fmaf(s, bnc[256 + tid], bnc[266 + tid]);
  }
}

extern "C" void kernel_launch(void* const* d_in, const int* in_sizes, int n_in,
                              void* d_out, int out_size, void* d_ws, size_t ws_size,
                              hipStream_t stream)
{
  const float* x  = (const float*)d_in[0];
  const float* w1 = (const float*)d_in[1];
  const float* w2 = (const float*)d_in[2];
  const float* w3 = (const float*)d_in[3];
  const float* w4 = (const float*)d_in[4];
  const float *g1=(const float*)d_in[5],  *b1=(const float*)d_in[6],
              *m1=(const float*)d_in[7],  *v1=(const float*)d_in[8];
  const float *g2=(const float*)d_in[9],  *b2=(const float*)d_in[10],
              *m2=(const float*)d_in[11], *v2=(const float*)d_in[12];
  const float *g3=(const float*)d_in[13], *b3=(const float*)d_in[14],
              *m3=(const float*)d_in[15], *v3=(const float*)d_in[16];
  const float *g4=(const float*)d_in[17], *b4=(const float*)d_in[18],
              *m4=(const float*)d_in[19], *v4=(const float*)d_in[20];
  float* out = (float*)d_out;

  char* ws = (char*)d_ws;
  _Float16* w1h = (_Float16*)(ws);             //  10,240 B
  _Float16* w2h = (_Float16*)(ws + 10240);     //  51,200 B
  _Float16* w3h = (_Float16*)(ws + 61440);     // 102,400 B
  _Float16* w4h = (_Float16*)(ws + 163840);    //  32,768 B
  float*    bnc = (float*)   (ws + 196608);    //   1,152 B

  k_prep<<<dim3(128), dim3(256), 0, stream>>>(w1, w2, w3, w4,
      g1,b1,m1,v1, g2,b2,m2,v2, g3,b3,m3,v3, g4,b4,m4,v4,
      w1h, w2h, w3h, w4h, bnc);
  k_fused<<<dim3(1024), dim3(256), 0, stream>>>(x, w1h, w2h, w3h, w4h, bnc, out);
}